// Round 1
// baseline (364.359 us; speedup 1.0000x reference)
//
#include <hip/hip_runtime.h>
#include <hip/hip_bf16.h>
#include <stdint.h>

#define D_DIM 1024
#define P_ROWS 8192
#define K_ROWS 131072
#define M_DIM 512
#define L_STEPS 64
#define BM 128
#define LDP 40   // LDS row pitch in bf16 elems (32 + 8 pad -> 80B, 4-bank shift)

typedef short bf16x8_t __attribute__((ext_vector_type(8)));
typedef float f32x4_t __attribute__((ext_vector_type(4)));

__device__ __forceinline__ uint32_t f2bf(float f) {
  union { float f; uint32_t u; } c; c.f = f;
  const uint32_t u = c.u;
  return (u + 0x7FFFu + ((u >> 16) & 1u)) >> 16;   // RNE, no NaN handling needed
}
__device__ __forceinline__ uint32_t pack2(float lo, float hi) {
  return f2bf(lo) | (f2bf(hi) << 16);
}

// v[d] += sum_i y[i] * X[i,d]
__global__ void xty_kernel(const float* __restrict__ X, const float* __restrict__ y,
                           float* __restrict__ v) {
  const int d0 = threadIdx.x * 4;
  float a0 = 0.f, a1 = 0.f, a2 = 0.f, a3 = 0.f;
  for (int i = blockIdx.x; i < P_ROWS; i += gridDim.x) {
    const float s = y[i];
    const float4 x = *reinterpret_cast<const float4*>(X + (size_t)i * D_DIM + d0);
    a0 += s * x.x; a1 += s * x.y; a2 += s * x.z; a3 += s * x.w;
  }
  atomicAdd(v + d0 + 0, a0);
  atomicAdd(v + d0 + 1, a1);
  atomicAdd(v + d0 + 2, a2);
  atomicAdd(v + d0 + 3, a3);
}

// wout[d] += sum_i (X[i,:].win) * X[i,d]   (= X^T X win, unscaled)
__global__ void xtxw_kernel(const float* __restrict__ X, const float* __restrict__ win,
                            float* __restrict__ wout) {
  __shared__ float red[4][D_DIM];
  const int lane = threadIdx.x & 63;
  const int wave = threadIdx.x >> 6;
  const int gw = blockIdx.x * 4 + wave;
  const int nw = gridDim.x * 4;
  float wv[16], acc[16];
#pragma unroll
  for (int q = 0; q < 4; ++q) {
    const float4 tv = *reinterpret_cast<const float4*>(win + q * 256 + lane * 4);
    wv[q*4+0] = tv.x; wv[q*4+1] = tv.y; wv[q*4+2] = tv.z; wv[q*4+3] = tv.w;
  }
#pragma unroll
  for (int j = 0; j < 16; ++j) acc[j] = 0.f;
  for (int i = gw; i < P_ROWS; i += nw) {
    const float* xr = X + (size_t)i * D_DIM;
    float xv[16];
    float dot = 0.f;
#pragma unroll
    for (int q = 0; q < 4; ++q) {
      const float4 tv = *reinterpret_cast<const float4*>(xr + q * 256 + lane * 4);
      xv[q*4+0] = tv.x; xv[q*4+1] = tv.y; xv[q*4+2] = tv.z; xv[q*4+3] = tv.w;
      dot += tv.x * wv[q*4+0] + tv.y * wv[q*4+1] + tv.z * wv[q*4+2] + tv.w * wv[q*4+3];
    }
#pragma unroll
    for (int m = 1; m < 64; m <<= 1) dot += __shfl_xor(dot, m);
#pragma unroll
    for (int j = 0; j < 16; ++j) acc[j] += dot * xv[j];
  }
#pragma unroll
  for (int q = 0; q < 4; ++q) {
    float4 tv;
    tv.x = acc[q*4+0]; tv.y = acc[q*4+1]; tv.z = acc[q*4+2]; tv.w = acc[q*4+3];
    *reinterpret_cast<float4*>(&red[wave][q * 256 + lane * 4]) = tv;
  }
  __syncthreads();
  const int d0 = threadIdx.x * 4;
#pragma unroll
  for (int j = 0; j < 4; ++j)
    atomicAdd(wout + d0 + j, red[0][d0+j] + red[1][d0+j] + red[2][d0+j] + red[3][d0+j]);
}

// rep = gamma * (64 v - 2016 eps u1/P + 41664 eps^2 u2/P^2); emit rep/(L*P) and rep/||rep||
__global__ void combine_kernel(const float* __restrict__ v, const float* __restrict__ u1,
                               const float* __restrict__ u2, const float* __restrict__ gamma_p,
                               float* __restrict__ rep_lin, float* __restrict__ repn) {
  __shared__ float sred[4];
  const float gamma = *gamma_p;
  const float eps = gamma / (float)L_STEPS;
  const float c1 = 2016.0f * eps / (float)P_ROWS;
  const float c2 = 41664.0f * eps * eps / ((float)P_ROWS * (float)P_ROWS);
  const int d0 = threadIdx.x * 4;
  float r[4];
  float ss = 0.f;
#pragma unroll
  for (int j = 0; j < 4; ++j) {
    const float val = gamma * ((float)L_STEPS * v[d0+j] - c1 * u1[d0+j] + c2 * u2[d0+j]);
    r[j] = val;
    ss += val * val;
  }
#pragma unroll
  for (int m = 1; m < 64; m <<= 1) ss += __shfl_xor(ss, m);
  if ((threadIdx.x & 63) == 0) sred[threadIdx.x >> 6] = ss;
  __syncthreads();
  const float norm = sqrtf(sred[0] + sred[1] + sred[2] + sred[3]);
  const float inv_norm = 1.0f / (norm + 1e-8f);
  const float lin_s = 1.0f / ((float)L_STEPS * (float)P_ROWS);
#pragma unroll
  for (int j = 0; j < 4; ++j) {
    rep_lin[d0+j] = r[j] * lin_s;
    repn[d0+j]    = r[j] * inv_norm;
  }
}

// Wn[m,d] = bf16(W[m,d] * repn[d])
__global__ void wn_kernel(const float* __restrict__ W, const float* __restrict__ repn,
                          ushort* __restrict__ Wn) {
  const int m = blockIdx.x;
  const int d0 = threadIdx.x * 4;
  const float4 w  = *reinterpret_cast<const float4*>(W + (size_t)m * D_DIM + d0);
  const float4 rn = *reinterpret_cast<const float4*>(repn + d0);
  ushort4 o;
  o.x = (ushort)f2bf(w.x * rn.x);
  o.y = (ushort)f2bf(w.y * rn.y);
  o.z = (ushort)f2bf(w.z * rn.z);
  o.w = (ushort)f2bf(w.w * rn.w);
  *reinterpret_cast<ushort4*>(Wn + (size_t)m * D_DIM + d0) = o;
}

// out[k] = dot(Xs[k,:], rep)/(L*P) + sum_m relu(dot(Xs[k,:], Wn[m,:]) + b1[m])*a[m] + b2
// BM=128 rows/block, full N=512, BK=32, double-buffered LDS, 8 waves (2M x 4N),
// wave tile 64x128 via 16x16x32 bf16 MFMA (4 m-frags x 8 n-frags).
__global__ __launch_bounds__(512, 2)
void fused_kernel(const float* __restrict__ Xs, const ushort* __restrict__ Wn,
                  const float* __restrict__ rep_lin, const float* __restrict__ b1,
                  const float* __restrict__ aw, const float* __restrict__ b2p,
                  float* __restrict__ out) {
  __shared__ ushort Alds[2][BM * LDP];
  __shared__ ushort Blds[2][M_DIM * LDP];
  __shared__ float mlp_acc[BM];
  __shared__ float lin_acc[BM];

  const int t = threadIdx.x;
  const int lane = t & 63;
  const int wid = t >> 6;
  const int wm = wid >> 2;     // 0..1
  const int wn = wid & 3;      // 0..3
  const size_t blockRow = (size_t)blockIdx.x * BM;

  if (t < BM) mlp_acc[t] = 0.f;

  const int arow = t >> 2;          // 0..127
  const int kchunk = (t & 3) * 8;   // 0,8,16,24

  const float*  Arow = Xs + (blockRow + (size_t)arow) * D_DIM + kchunk;
  const ushort* Brow = Wn + (size_t)arow * D_DIM + kchunk;

  float linreg = 0.f;

  // ---- stage step 0 into buffer 0 ----
  {
    const float4 a0 = *reinterpret_cast<const float4*>(Arow);
    const float4 a1 = *reinterpret_cast<const float4*>(Arow + 4);
    const uint4 b0 = *reinterpret_cast<const uint4*>(Brow + 0 * 128 * D_DIM);
    const uint4 b1q = *reinterpret_cast<const uint4*>(Brow + 1 * 128 * D_DIM);
    const uint4 b2q = *reinterpret_cast<const uint4*>(Brow + 2 * 128 * D_DIM);
    const uint4 b3q = *reinterpret_cast<const uint4*>(Brow + 3 * 128 * D_DIM);
    const float4 r0 = *reinterpret_cast<const float4*>(rep_lin + kchunk);
    const float4 r1 = *reinterpret_cast<const float4*>(rep_lin + kchunk + 4);
    linreg += a0.x*r0.x + a0.y*r0.y + a0.z*r0.z + a0.w*r0.w
            + a1.x*r1.x + a1.y*r1.y + a1.z*r1.z + a1.w*r1.w;
    uint4 ap;
    ap.x = pack2(a0.x, a0.y); ap.y = pack2(a0.z, a0.w);
    ap.z = pack2(a1.x, a1.y); ap.w = pack2(a1.z, a1.w);
    *reinterpret_cast<uint4*>(&Alds[0][arow * LDP + kchunk]) = ap;
    *reinterpret_cast<uint4*>(&Blds[0][(arow +   0) * LDP + kchunk]) = b0;
    *reinterpret_cast<uint4*>(&Blds[0][(arow + 128) * LDP + kchunk]) = b1q;
    *reinterpret_cast<uint4*>(&Blds[0][(arow + 256) * LDP + kchunk]) = b2q;
    *reinterpret_cast<uint4*>(&Blds[0][(arow + 384) * LDP + kchunk]) = b3q;
  }

  f32x4_t acc[4][8];
#pragma unroll
  for (int mi = 0; mi < 4; ++mi)
#pragma unroll
    for (int ni = 0; ni < 8; ++ni)
      acc[mi][ni] = f32x4_t{0.f, 0.f, 0.f, 0.f};

  __syncthreads();

  const int fr = lane & 15;    // frag row/col
  const int kg = lane >> 4;    // k group 0..3
  const int aoff = (wm * 64 + fr) * LDP + kg * 8;
  const int boff = (wn * 128 + fr) * LDP + kg * 8;

  for (int s = 0; s < 32; ++s) {
    const int cur = s & 1;
    float4 na0, na1; uint4 nb0, nb1, nb2, nb3;
    if (s < 31) {
      const float*  An = Arow + (s + 1) * 32;
      const ushort* Bn = Brow + (s + 1) * 32;
      na0 = *reinterpret_cast<const float4*>(An);
      na1 = *reinterpret_cast<const float4*>(An + 4);
      nb0 = *reinterpret_cast<const uint4*>(Bn + 0 * 128 * D_DIM);
      nb1 = *reinterpret_cast<const uint4*>(Bn + 1 * 128 * D_DIM);
      nb2 = *reinterpret_cast<const uint4*>(Bn + 2 * 128 * D_DIM);
      nb3 = *reinterpret_cast<const uint4*>(Bn + 3 * 128 * D_DIM);
    }
    const ushort* Ab = &Alds[cur][0];
    const ushort* Bb = &Blds[cur][0];
    bf16x8_t afr[4], bfr[8];
#pragma unroll
    for (int mi = 0; mi < 4; ++mi)
      afr[mi] = *reinterpret_cast<const bf16x8_t*>(Ab + aoff + mi * 16 * LDP);
#pragma unroll
    for (int ni = 0; ni < 8; ++ni)
      bfr[ni] = *reinterpret_cast<const bf16x8_t*>(Bb + boff + ni * 16 * LDP);
#pragma unroll
    for (int mi = 0; mi < 4; ++mi)
#pragma unroll
      for (int ni = 0; ni < 8; ++ni)
        acc[mi][ni] = __builtin_amdgcn_mfma_f32_16x16x32_bf16(afr[mi], bfr[ni], acc[mi][ni], 0, 0, 0);
    if (s < 31) {
      const int nxt = cur ^ 1;
      const float* rl = rep_lin + (s + 1) * 32 + kchunk;
      const float4 r0 = *reinterpret_cast<const float4*>(rl);
      const float4 r1 = *reinterpret_cast<const float4*>(rl + 4);
      linreg += na0.x*r0.x + na0.y*r0.y + na0.z*r0.z + na0.w*r0.w
              + na1.x*r1.x + na1.y*r1.y + na1.z*r1.z + na1.w*r1.w;
      uint4 ap;
      ap.x = pack2(na0.x, na0.y); ap.y = pack2(na0.z, na0.w);
      ap.z = pack2(na1.x, na1.y); ap.w = pack2(na1.z, na1.w);
      *reinterpret_cast<uint4*>(&Alds[nxt][arow * LDP + kchunk]) = ap;
      *reinterpret_cast<uint4*>(&Blds[nxt][(arow +   0) * LDP + kchunk]) = nb0;
      *reinterpret_cast<uint4*>(&Blds[nxt][(arow + 128) * LDP + kchunk]) = nb1;
      *reinterpret_cast<uint4*>(&Blds[nxt][(arow + 256) * LDP + kchunk]) = nb2;
      *reinterpret_cast<uint4*>(&Blds[nxt][(arow + 384) * LDP + kchunk]) = nb3;
    }
    __syncthreads();
  }

  // ---- epilogue ----
  linreg += __shfl_xor(linreg, 1);
  linreg += __shfl_xor(linreg, 2);
  if ((t & 3) == 0) lin_acc[arow] = linreg;

  float b1r[8], ar[8];
#pragma unroll
  for (int ni = 0; ni < 8; ++ni) {
    const int c = wn * 128 + ni * 16 + fr;
    b1r[ni] = b1[c];
    ar[ni]  = aw[c];
  }
#pragma unroll
  for (int mi = 0; mi < 4; ++mi) {
#pragma unroll
    for (int r = 0; r < 4; ++r) {
      float sum = 0.f;
#pragma unroll
      for (int ni = 0; ni < 8; ++ni) {
        const float h = acc[mi][ni][r] + b1r[ni];
        sum += fmaxf(h, 0.f) * ar[ni];
      }
      sum += __shfl_xor(sum, 1);
      sum += __shfl_xor(sum, 2);
      sum += __shfl_xor(sum, 4);
      sum += __shfl_xor(sum, 8);
      if (fr == 0) {
        const int row = wm * 64 + mi * 16 + kg * 4 + r;
        atomicAdd(&mlp_acc[row], sum);
      }
    }
  }
  __syncthreads();
  if (t < BM)
    out[blockRow + t] = lin_acc[t] + mlp_acc[t] + b2p[0];
}

extern "C" void kernel_launch(void* const* d_in, const int* in_sizes, int n_in,
                              void* d_out, int out_size, void* d_ws, size_t ws_size,
                              hipStream_t stream) {
  const float* X     = (const float*)d_in[0];
  const float* y     = (const float*)d_in[1];
  const float* Xs    = (const float*)d_in[2];
  const float* gamma = (const float*)d_in[3];
  const float* W     = (const float*)d_in[4];
  const float* a     = (const float*)d_in[5];
  const float* b1    = (const float*)d_in[6];
  const float* b2    = (const float*)d_in[7];
  float* out = (float*)d_out;

  char* ws = (char*)d_ws;
  float*  v       = (float*)(ws + 0);
  float*  u1      = (float*)(ws + 4096);
  float*  u2      = (float*)(ws + 8192);
  float*  rep_lin = (float*)(ws + 12288);
  float*  repn    = (float*)(ws + 16384);
  ushort* Wn      = (ushort*)(ws + 20480);

  hipMemsetAsync(ws, 0, 3 * 4096, stream);
  hipLaunchKernelGGL(xty_kernel,    dim3(128), dim3(256), 0, stream, X, y, v);
  hipLaunchKernelGGL(xtxw_kernel,   dim3(128), dim3(256), 0, stream, X, v, u1);
  hipLaunchKernelGGL(xtxw_kernel,   dim3(128), dim3(256), 0, stream, X, u1, u2);
  hipLaunchKernelGGL(combine_kernel, dim3(1),  dim3(256), 0, stream, v, u1, u2, gamma, rep_lin, repn);
  hipLaunchKernelGGL(wn_kernel,     dim3(M_DIM), dim3(256), 0, stream, W, repn, Wn);
  hipLaunchKernelGGL(fused_kernel,  dim3(K_ROWS / BM), dim3(512), 0, stream,
                     Xs, Wn, rep_lin, b1, a, b2, out);
}

// Round 2
// 342.564 us; speedup vs baseline: 1.0636x; 1.0636x over previous
//
#include <hip/hip_runtime.h>
#include <hip/hip_bf16.h>
#include <stdint.h>

#define D_DIM 1024
#define P_ROWS 8192
#define K_ROWS 131072
#define M_DIM 512
#define L_STEPS 64
#define BM 128

typedef short bf16x8_t __attribute__((ext_vector_type(8)));
typedef float f32x4_t __attribute__((ext_vector_type(4)));

typedef const __attribute__((address_space(1))) void* gas_t;
typedef __attribute__((address_space(3))) void* las_t;

__device__ __forceinline__ uint32_t f2bf(float f) {
  union { float f; uint32_t u; } c; c.f = f;
  const uint32_t u = c.u;
  return (u + 0x7FFFu + ((u >> 16) & 1u)) >> 16;   // RNE
}

// v[d] += sum_i y[i] * X[i,d]
__global__ void xty_kernel(const float* __restrict__ X, const float* __restrict__ y,
                           float* __restrict__ v) {
  const int d0 = threadIdx.x * 4;
  float a0 = 0.f, a1 = 0.f, a2 = 0.f, a3 = 0.f;
  for (int i = blockIdx.x; i < P_ROWS; i += gridDim.x) {
    const float s = y[i];
    const float4 x = *reinterpret_cast<const float4*>(X + (size_t)i * D_DIM + d0);
    a0 += s * x.x; a1 += s * x.y; a2 += s * x.z; a3 += s * x.w;
  }
  atomicAdd(v + d0 + 0, a0);
  atomicAdd(v + d0 + 1, a1);
  atomicAdd(v + d0 + 2, a2);
  atomicAdd(v + d0 + 3, a3);
}

// wout[d] += sum_i (X[i,:].win) * X[i,d]
__global__ void xtxw_kernel(const float* __restrict__ X, const float* __restrict__ win,
                            float* __restrict__ wout) {
  __shared__ float red[4][D_DIM];
  const int lane = threadIdx.x & 63;
  const int wave = threadIdx.x >> 6;
  const int gw = blockIdx.x * 4 + wave;
  const int nw = gridDim.x * 4;
  float wv[16], acc[16];
#pragma unroll
  for (int q = 0; q < 4; ++q) {
    const float4 tv = *reinterpret_cast<const float4*>(win + q * 256 + lane * 4);
    wv[q*4+0] = tv.x; wv[q*4+1] = tv.y; wv[q*4+2] = tv.z; wv[q*4+3] = tv.w;
  }
#pragma unroll
  for (int j = 0; j < 16; ++j) acc[j] = 0.f;
  for (int i = gw; i < P_ROWS; i += nw) {
    const float* xr = X + (size_t)i * D_DIM;
    float xv[16];
    float dot = 0.f;
#pragma unroll
    for (int q = 0; q < 4; ++q) {
      const float4 tv = *reinterpret_cast<const float4*>(xr + q * 256 + lane * 4);
      xv[q*4+0] = tv.x; xv[q*4+1] = tv.y; xv[q*4+2] = tv.z; xv[q*4+3] = tv.w;
      dot += tv.x * wv[q*4+0] + tv.y * wv[q*4+1] + tv.z * wv[q*4+2] + tv.w * wv[q*4+3];
    }
#pragma unroll
    for (int m = 1; m < 64; m <<= 1) dot += __shfl_xor(dot, m);
#pragma unroll
    for (int j = 0; j < 16; ++j) acc[j] += dot * xv[j];
  }
#pragma unroll
  for (int q = 0; q < 4; ++q) {
    float4 tv;
    tv.x = acc[q*4+0]; tv.y = acc[q*4+1]; tv.z = acc[q*4+2]; tv.w = acc[q*4+3];
    *reinterpret_cast<float4*>(&red[wave][q * 256 + lane * 4]) = tv;
  }
  __syncthreads();
  const int d0 = threadIdx.x * 4;
#pragma unroll
  for (int j = 0; j < 4; ++j)
    atomicAdd(wout + d0 + j, red[0][d0+j] + red[1][d0+j] + red[2][d0+j] + red[3][d0+j]);
}

// rep = gamma*(64 v - 2016 eps u1/P + 41664 eps^2 u2/P^2); emit rep/(L*P) and rep/||rep||
__global__ void combine_kernel(const float* __restrict__ v, const float* __restrict__ u1,
                               const float* __restrict__ u2, const float* __restrict__ gamma_p,
                               float* __restrict__ rep_lin, float* __restrict__ repn) {
  __shared__ float sred[4];
  const float gamma = *gamma_p;
  const float eps = gamma / (float)L_STEPS;
  const float c1 = 2016.0f * eps / (float)P_ROWS;
  const float c2 = 41664.0f * eps * eps / ((float)P_ROWS * (float)P_ROWS);
  const int d0 = threadIdx.x * 4;
  float r[4];
  float ss = 0.f;
#pragma unroll
  for (int j = 0; j < 4; ++j) {
    const float val = gamma * ((float)L_STEPS * v[d0+j] - c1 * u1[d0+j] + c2 * u2[d0+j]);
    r[j] = val;
    ss += val * val;
  }
#pragma unroll
  for (int m = 1; m < 64; m <<= 1) ss += __shfl_xor(ss, m);
  if ((threadIdx.x & 63) == 0) sred[threadIdx.x >> 6] = ss;
  __syncthreads();
  const float norm = sqrtf(sred[0] + sred[1] + sred[2] + sred[3]);
  const float inv_norm = 1.0f / (norm + 1e-8f);
  const float lin_s = 1.0f / ((float)L_STEPS * (float)P_ROWS);
#pragma unroll
  for (int j = 0; j < 4; ++j) {
    rep_lin[d0+j] = r[j] * lin_s;
    repn[d0+j]    = r[j] * inv_norm;
  }
}

// WnF fragment-major: elem ((s*32+f)*64+l)*8 + j = bf16(W[f*16+(l&15)][s*32+(l>>4)*8+j] * repn[d])
__global__ void wn_frag_kernel(const float* __restrict__ W, const float* __restrict__ repn,
                               ushort* __restrict__ WnF) {
  const int gid = blockIdx.x * 256 + threadIdx.x;   // 65536
  const int l = gid & 63;
  const int f = (gid >> 6) & 31;
  const int s = gid >> 11;
  const int m = f * 16 + (l & 15);
  const int d0 = s * 32 + ((l >> 4) << 3);
  const float4 w0 = *reinterpret_cast<const float4*>(W + (size_t)m * D_DIM + d0);
  const float4 w1 = *reinterpret_cast<const float4*>(W + (size_t)m * D_DIM + d0 + 4);
  const float4 r0 = *reinterpret_cast<const float4*>(repn + d0);
  const float4 r1 = *reinterpret_cast<const float4*>(repn + d0 + 4);
  uint32_t p0 = f2bf(w0.x*r0.x) | (f2bf(w0.y*r0.y) << 16);
  uint32_t p1 = f2bf(w0.z*r0.z) | (f2bf(w0.w*r0.w) << 16);
  uint32_t p2 = f2bf(w1.x*r1.x) | (f2bf(w1.y*r1.y) << 16);
  uint32_t p3 = f2bf(w1.z*r1.z) | (f2bf(w1.w*r1.w) << 16);
  uint4 o; o.x = p0; o.y = p1; o.z = p2; o.w = p3;
  *reinterpret_cast<uint4*>(WnF + (size_t)gid * 8) = o;
}

// Fused: out[k] = dot(Xs[k],rep_lin) + sum_m relu(dot(Xs[k],Wn[m])+b1[m])*a[m] + b2
// BM=128, BN=512(full), BK=32, 8 waves (2Mx4N), wave tile 64x128, 16x16x32 bf16 MFMA.
// A: f32 via global_load_lds w/ pre-swizzled source (XOR chunk swizzle), 3-deep buffers.
// B: fragment-major bf16 via global_load_lds, 2-deep, lane-linear ds_reads (0 conflicts).
// Counted vmcnt(2) before raw s_barrier keeps A(s+2) in flight across barriers.
__global__ __launch_bounds__(512, 2)
void fused_kernel(const float* __restrict__ Xs, const ushort* __restrict__ WnF,
                  const float* __restrict__ rep_lin, const float* __restrict__ b1,
                  const float* __restrict__ aw, const float* __restrict__ b2p,
                  float* __restrict__ out) {
  __shared__ float  Af[3 * 4096];    // 3 x 16KB f32 A tiles (swizzled)
  __shared__ ushort Bh[2 * 16384];   // 2 x 32KB bf16 B tiles (fragment-major)
  __shared__ float  repl[D_DIM];
  __shared__ float  mlp_acc[BM];
  __shared__ float  lin_acc[BM];

  const int t = threadIdx.x;
  const int lane = t & 63;
  const int wid = t >> 6;
  const int wm = wid >> 2;
  const int wn = wid & 3;
  const int fr = lane & 15;
  const int kg = lane >> 4;
  const size_t blockRow = (size_t)blockIdx.x * BM;

  char* AfB = (char*)Af;
  char* BhB = (char*)Bh;
  const char* WnB = (const char*)WnF;
  const char* replB = (const char*)repl;

  // per-lane pre-swizzled global A source (chunk c = (lane&7)^(lane>>3))
  const char* gA0 = (const char*)Xs
      + (blockRow + (size_t)wid * 16 + (lane >> 3)) * (D_DIM * 4)
      + (size_t)(((lane & 7) ^ (lane >> 3)) * 16);
  const char* gA1 = gA0 + (size_t)8 * (D_DIM * 4);

  // ds_read offsets (within one A buffer)
  const int aoff0 = (wm * 64 + fr) * 128 + (((kg * 2)     ^ (lane & 7)) * 16);
  const int aoff1 = (wm * 64 + fr) * 128 + (((kg * 2 + 1) ^ (lane & 7)) * 16);
  const int rowL = t >> 2;
  const int cL = (t & 3) * 2;
  const int loffA0 = rowL * 128 + ((cL      ^ (rowL & 7)) * 16);
  const int loffA1 = rowL * 128 + (((cL | 1) ^ (rowL & 7)) * 16);

  f32x4_t acc[4][8];
#pragma unroll
  for (int mi = 0; mi < 4; ++mi)
#pragma unroll
    for (int ni = 0; ni < 8; ++ni)
      acc[mi][ni] = f32x4_t{0.f, 0.f, 0.f, 0.f};
  float linreg = 0.f;

  // ---- staging helpers ----
  auto stageB = [&](int sn) {
    const char* src = WnB + (size_t)sn * 32768 + (size_t)wid * 4096 + (size_t)lane * 16;
    char* dst = BhB + (size_t)(sn & 1) * 32768 + (size_t)wid * 4096;
#pragma unroll
    for (int j = 0; j < 4; ++j)
      __builtin_amdgcn_global_load_lds((gas_t)(src + j * 1024), (las_t)(dst + j * 1024), 16, 0, 0);
  };
  auto stageA = [&](int s2) {
    char* dst = AfB + (size_t)(s2 % 3) * 16384 + (size_t)wid * 2048;
    __builtin_amdgcn_global_load_lds((gas_t)(gA0 + (size_t)s2 * 128), (las_t)dst, 16, 0, 0);
    __builtin_amdgcn_global_load_lds((gas_t)(gA1 + (size_t)s2 * 128), (las_t)(dst + 1024), 16, 0, 0);
  };
  auto compute = [&](int s) {
    const char* Ab = AfB + (size_t)(s % 3) * 16384;
    const char* Bb = BhB + (size_t)(s & 1) * 32768;
    bf16x8_t bfr[8];
#pragma unroll
    for (int ni = 0; ni < 8; ++ni)
      bfr[ni] = *reinterpret_cast<const bf16x8_t*>(Bb + wn * 8192 + ni * 1024 + lane * 16);
    bf16x8_t afr[4];
#pragma unroll
    for (int mi = 0; mi < 4; ++mi) {
      f32x4_t v0 = *reinterpret_cast<const f32x4_t*>(Ab + aoff0 + mi * 2048);
      f32x4_t v1 = *reinterpret_cast<const f32x4_t*>(Ab + aoff1 + mi * 2048);
      uint32_t p0, p1, p2, p3;
      asm("v_cvt_pk_bf16_f32 %0, %1, %2" : "=v"(p0) : "v"(v0[0]), "v"(v0[1]));
      asm("v_cvt_pk_bf16_f32 %0, %1, %2" : "=v"(p1) : "v"(v0[2]), "v"(v0[3]));
      asm("v_cvt_pk_bf16_f32 %0, %1, %2" : "=v"(p2) : "v"(v1[0]), "v"(v1[1]));
      asm("v_cvt_pk_bf16_f32 %0, %1, %2" : "=v"(p3) : "v"(v1[2]), "v"(v1[3]));
      union { uint32_t u[4]; bf16x8_t h; } cv;
      cv.u[0] = p0; cv.u[1] = p1; cv.u[2] = p2; cv.u[3] = p3;
      afr[mi] = cv.h;
    }
#pragma unroll
    for (int mi = 0; mi < 4; ++mi)
#pragma unroll
      for (int ni = 0; ni < 8; ++ni)
        acc[mi][ni] = __builtin_amdgcn_mfma_f32_16x16x32_bf16(afr[mi], bfr[ni], acc[mi][ni], 0, 0, 0);
    // linear term from f32 A in LDS
    f32x4_t la0 = *reinterpret_cast<const f32x4_t*>(Ab + loffA0);
    f32x4_t la1 = *reinterpret_cast<const f32x4_t*>(Ab + loffA1);
    f32x4_t lr0 = *reinterpret_cast<const f32x4_t*>(replB + s * 128 + (t & 3) * 32);
    f32x4_t lr1 = *reinterpret_cast<const f32x4_t*>(replB + s * 128 + (t & 3) * 32 + 16);
    linreg += la0[0]*lr0[0] + la0[1]*lr0[1] + la0[2]*lr0[2] + la0[3]*lr0[3]
            + la1[0]*lr1[0] + la1[1]*lr1[1] + la1[2]*lr1[2] + la1[3]*lr1[3];
  };

  // ---- prologue ----
  stageB(0);
  stageA(0);
  stageA(1);
  if (t < BM) mlp_acc[t] = 0.f;
  repl[t] = rep_lin[t];
  repl[t + 512] = rep_lin[t + 512];
  asm volatile("s_waitcnt vmcnt(0)" ::: "memory");
  __syncthreads();

  // ---- main loop: steps 0..29 steady-state ----
  for (int s = 0; s < 30; ++s) {
    stageB(s + 1);
    stageA(s + 2);
    __builtin_amdgcn_sched_barrier(0);
    compute(s);
    asm volatile("s_waitcnt vmcnt(2)" ::: "memory");
    __builtin_amdgcn_sched_barrier(0);
    __builtin_amdgcn_s_barrier();
  }
  // step 30
  stageB(31);
  __builtin_amdgcn_sched_barrier(0);
  compute(30);
  asm volatile("s_waitcnt vmcnt(0)" ::: "memory");
  __builtin_amdgcn_sched_barrier(0);
  __builtin_amdgcn_s_barrier();
  // step 31
  compute(31);

  // ---- epilogue ----
  linreg += __shfl_xor(linreg, 1);
  linreg += __shfl_xor(linreg, 2);
  if ((t & 3) == 0) lin_acc[rowL] = linreg;

  float b1r[8], ar[8];
#pragma unroll
  for (int ni = 0; ni < 8; ++ni) {
    const int c = wn * 128 + ni * 16 + fr;
    b1r[ni] = b1[c];
    ar[ni]  = aw[c];
  }
#pragma unroll
  for (int mi = 0; mi < 4; ++mi) {
#pragma unroll
    for (int r = 0; r < 4; ++r) {
      float sum = 0.f;
#pragma unroll
      for (int ni = 0; ni < 8; ++ni) {
        const float h = acc[mi][ni][r] + b1r[ni];
        sum += fmaxf(h, 0.f) * ar[ni];
      }
      sum += __shfl_xor(sum, 1);
      sum += __shfl_xor(sum, 2);
      sum += __shfl_xor(sum, 4);
      sum += __shfl_xor(sum, 8);
      if (fr == 0) {
        const int row = wm * 64 + mi * 16 + kg * 4 + r;
        atomicAdd(&mlp_acc[row], sum);
      }
    }
  }
  __syncthreads();
  if (t < BM)
    out[blockRow + t] = lin_acc[t] + mlp_acc[t] + b2p[0];
}

extern "C" void kernel_launch(void* const* d_in, const int* in_sizes, int n_in,
                              void* d_out, int out_size, void* d_ws, size_t ws_size,
                              hipStream_t stream) {
  const float* X     = (const float*)d_in[0];
  const float* y     = (const float*)d_in[1];
  const float* Xs    = (const float*)d_in[2];
  const float* gamma = (const float*)d_in[3];
  const float* W     = (const float*)d_in[4];
  const float* a     = (const float*)d_in[5];
  const float* b1    = (const float*)d_in[6];
  const float* b2    = (const float*)d_in[7];
  float* out = (float*)d_out;

  char* ws = (char*)d_ws;
  float*  v       = (float*)(ws + 0);
  float*  u1      = (float*)(ws + 4096);
  float*  u2      = (float*)(ws + 8192);
  float*  rep_lin = (float*)(ws + 12288);
  float*  repn    = (float*)(ws + 16384);
  ushort* WnF     = (ushort*)(ws + 20480);

  hipMemsetAsync(ws, 0, 3 * 4096, stream);
  hipLaunchKernelGGL(xty_kernel,     dim3(256), dim3(256), 0, stream, X, y, v);
  hipLaunchKernelGGL(xtxw_kernel,    dim3(256), dim3(256), 0, stream, X, v, u1);
  hipLaunchKernelGGL(xtxw_kernel,    dim3(256), dim3(256), 0, stream, X, u1, u2);
  hipLaunchKernelGGL(combine_kernel, dim3(1),   dim3(256), 0, stream, v, u1, u2, gamma, rep_lin, repn);
  hipLaunchKernelGGL(wn_frag_kernel, dim3(256), dim3(256), 0, stream, W, repn, WnF);
  hipLaunchKernelGGL(fused_kernel,   dim3(K_ROWS / BM), dim3(512), 0, stream,
                     Xs, WnF, rep_lin, b1, a, b2, out);
}

// Round 3
// 325.507 us; speedup vs baseline: 1.1194x; 1.0524x over previous
//
#include <hip/hip_runtime.h>
#include <hip/hip_bf16.h>
#include <stdint.h>

#define D_DIM 1024
#define P_ROWS 8192
#define K_ROWS 131072
#define M_DIM 512
#define L_STEPS 64
#define BM 128

typedef short bf16x8_t __attribute__((ext_vector_type(8)));
typedef float f32x4_t __attribute__((ext_vector_type(4)));

typedef const __attribute__((address_space(1))) void* gas_t;
typedef __attribute__((address_space(3))) void* las_t;

__device__ __forceinline__ uint32_t f2bf(float f) {
  union { float f; uint32_t u; } c; c.f = f;
  const uint32_t u = c.u;
  return (u + 0x7FFFu + ((u >> 16) & 1u)) >> 16;   // RNE
}
__device__ __forceinline__ uint32_t pack2(float lo, float hi) {
  return f2bf(lo) | (f2bf(hi) << 16);
}

// v[d] += sum_i y[i] * X[i,d]
__global__ void xty_kernel(const float* __restrict__ X, const float* __restrict__ y,
                           float* __restrict__ v) {
  const int d0 = threadIdx.x * 4;
  float a0 = 0.f, a1 = 0.f, a2 = 0.f, a3 = 0.f;
  for (int i = blockIdx.x; i < P_ROWS; i += gridDim.x) {
    const float s = y[i];
    const float4 x = *reinterpret_cast<const float4*>(X + (size_t)i * D_DIM + d0);
    a0 += s * x.x; a1 += s * x.y; a2 += s * x.z; a3 += s * x.w;
  }
  atomicAdd(v + d0 + 0, a0);
  atomicAdd(v + d0 + 1, a1);
  atomicAdd(v + d0 + 2, a2);
  atomicAdd(v + d0 + 3, a3);
}

// wout[d] += sum_i (X[i,:].win) * X[i,d]
__global__ void xtxw_kernel(const float* __restrict__ X, const float* __restrict__ win,
                            float* __restrict__ wout) {
  __shared__ float red[4][D_DIM];
  const int lane = threadIdx.x & 63;
  const int wave = threadIdx.x >> 6;
  const int gw = blockIdx.x * 4 + wave;
  const int nw = gridDim.x * 4;
  float wv[16], acc[16];
#pragma unroll
  for (int q = 0; q < 4; ++q) {
    const float4 tv = *reinterpret_cast<const float4*>(win + q * 256 + lane * 4);
    wv[q*4+0] = tv.x; wv[q*4+1] = tv.y; wv[q*4+2] = tv.z; wv[q*4+3] = tv.w;
  }
#pragma unroll
  for (int j = 0; j < 16; ++j) acc[j] = 0.f;
  for (int i = gw; i < P_ROWS; i += nw) {
    const float* xr = X + (size_t)i * D_DIM;
    float xv[16];
    float dot = 0.f;
#pragma unroll
    for (int q = 0; q < 4; ++q) {
      const float4 tv = *reinterpret_cast<const float4*>(xr + q * 256 + lane * 4);
      xv[q*4+0] = tv.x; xv[q*4+1] = tv.y; xv[q*4+2] = tv.z; xv[q*4+3] = tv.w;
      dot += tv.x * wv[q*4+0] + tv.y * wv[q*4+1] + tv.z * wv[q*4+2] + tv.w * wv[q*4+3];
    }
#pragma unroll
    for (int m = 1; m < 64; m <<= 1) dot += __shfl_xor(dot, m);
#pragma unroll
    for (int j = 0; j < 16; ++j) acc[j] += dot * xv[j];
  }
#pragma unroll
  for (int q = 0; q < 4; ++q) {
    float4 tv;
    tv.x = acc[q*4+0]; tv.y = acc[q*4+1]; tv.z = acc[q*4+2]; tv.w = acc[q*4+3];
    *reinterpret_cast<float4*>(&red[wave][q * 256 + lane * 4]) = tv;
  }
  __syncthreads();
  const int d0 = threadIdx.x * 4;
#pragma unroll
  for (int j = 0; j < 4; ++j)
    atomicAdd(wout + d0 + j, red[0][d0+j] + red[1][d0+j] + red[2][d0+j] + red[3][d0+j]);
}

// rep = gamma*(64 v - 2016 eps u1/P + 41664 eps^2 u2/P^2); emit rep/(L*P) and rep/||rep||
__global__ void combine_kernel(const float* __restrict__ v, const float* __restrict__ u1,
                               const float* __restrict__ u2, const float* __restrict__ gamma_p,
                               float* __restrict__ rep_lin, float* __restrict__ repn) {
  __shared__ float sred[4];
  const float gamma = *gamma_p;
  const float eps = gamma / (float)L_STEPS;
  const float c1 = 2016.0f * eps / (float)P_ROWS;
  const float c2 = 41664.0f * eps * eps / ((float)P_ROWS * (float)P_ROWS);
  const int d0 = threadIdx.x * 4;
  float r[4];
  float ss = 0.f;
#pragma unroll
  for (int j = 0; j < 4; ++j) {
    const float val = gamma * ((float)L_STEPS * v[d0+j] - c1 * u1[d0+j] + c2 * u2[d0+j]);
    r[j] = val;
    ss += val * val;
  }
#pragma unroll
  for (int m = 1; m < 64; m <<= 1) ss += __shfl_xor(ss, m);
  if ((threadIdx.x & 63) == 0) sred[threadIdx.x >> 6] = ss;
  __syncthreads();
  const float norm = sqrtf(sred[0] + sred[1] + sred[2] + sred[3]);
  const float inv_norm = 1.0f / (norm + 1e-8f);
  const float lin_s = 1.0f / ((float)L_STEPS * (float)P_ROWS);
#pragma unroll
  for (int j = 0; j < 4; ++j) {
    rep_lin[d0+j] = r[j] * lin_s;
    repn[d0+j]    = r[j] * inv_norm;
  }
}

// WnF fragment-major: elem ((s*32+f)*64+l)*8 + j = bf16(W[f*16+(l&15)][s*32+(l>>4)*8+j] * repn[d])
__global__ void wn_frag_kernel(const float* __restrict__ W, const float* __restrict__ repn,
                               ushort* __restrict__ WnF) {
  const int gid = blockIdx.x * 256 + threadIdx.x;   // 65536
  const int l = gid & 63;
  const int f = (gid >> 6) & 31;
  const int s = gid >> 11;
  const int m = f * 16 + (l & 15);
  const int d0 = s * 32 + ((l >> 4) << 3);
  const float4 w0 = *reinterpret_cast<const float4*>(W + (size_t)m * D_DIM + d0);
  const float4 w1 = *reinterpret_cast<const float4*>(W + (size_t)m * D_DIM + d0 + 4);
  const float4 r0 = *reinterpret_cast<const float4*>(repn + d0);
  const float4 r1 = *reinterpret_cast<const float4*>(repn + d0 + 4);
  uint4 o;
  o.x = f2bf(w0.x*r0.x) | (f2bf(w0.y*r0.y) << 16);
  o.y = f2bf(w0.z*r0.z) | (f2bf(w0.w*r0.w) << 16);
  o.z = f2bf(w1.x*r1.x) | (f2bf(w1.y*r1.y) << 16);
  o.w = f2bf(w1.z*r1.z) | (f2bf(w1.w*r1.w) << 16);
  *reinterpret_cast<uint4*>(WnF + (size_t)gid * 8) = o;
}

// Fused: out[k] = dot(Xs[k],rep_lin) + sum_m relu(dot(Xs[k],Wn[m])+b1[m])*a[m] + b2
// m201-ordered steps: ds_read(s) -> issue A(s+1)->regs + B(s+2) DMA -> MFMA ->
// lin/cvt/ds_write A(s+1) bf16 fragment-linear -> vmcnt(4) lgkmcnt(0) -> s_barrier.
// B: 3 x 32KB buffers, DMA 2-ahead (4 loads stay in flight across barrier).
// A: global->reg (1-ahead) -> bf16 fragment-linear LDS (0-conflict b128 both sides).
__global__ __launch_bounds__(512, 2)
void fused_kernel(const float* __restrict__ Xs, const ushort* __restrict__ WnF,
                  const float* __restrict__ rep_lin, const float* __restrict__ b1,
                  const float* __restrict__ aw, const float* __restrict__ b2p,
                  float* __restrict__ out) {
  __shared__ __align__(16) ushort Bh[3 * 16384];   // 96 KB
  __shared__ __align__(16) ushort Ah[2 * 4096];    // 16 KB
  __shared__ float mlp_acc[BM];
  __shared__ float lin_acc[BM];

  const int t = threadIdx.x;
  const int lane = t & 63;
  const int wid = t >> 6;
  const int wm = wid >> 2;     // 0..1
  const int wn = wid & 3;      // 0..3
  const int fr = lane & 15;
  const int kg = lane >> 4;
  const int R  = t >> 2;       // staging row 0..127
  const int cq = t & 3;        // staging col-quad
  const size_t blockRow = (size_t)blockIdx.x * BM;

  char* BhB = (char*)Bh;
  char* AhB = (char*)Ah;
  const char* WnB = (const char*)WnF;
  const char* gA = (const char*)Xs + (blockRow + (size_t)R) * (D_DIM * 4) + (size_t)cq * 32;
  const char* gR = (const char*)rep_lin + cq * 32;

  const int aw_off  = (R >> 4) * 1024 + (((cq << 4) | (R & 15)) * 16);
  const int ar_base = (wm * 4) * 1024 + lane * 16;   // + mi*1024
  const int br_base = wn * 8192 + lane * 16;         // + ni*1024

  auto stageB = [&](int sn) {
    const char* src = WnB + (size_t)sn * 32768 + (size_t)wid * 4096 + (size_t)lane * 16;
    char* dst = BhB + (size_t)(sn % 3) * 32768 + (size_t)wid * 4096;
#pragma unroll
    for (int j = 0; j < 4; ++j)
      __builtin_amdgcn_global_load_lds((gas_t)(src + j * 1024), (las_t)(dst + j * 1024), 16, 0, 0);
  };

  float linreg = 0.f;
  auto stageA_math = [&](int sn, const float4& a0, const float4& a1,
                         const float4& r0, const float4& r1) {
    linreg += a0.x*r0.x + a0.y*r0.y + a0.z*r0.z + a0.w*r0.w
            + a1.x*r1.x + a1.y*r1.y + a1.z*r1.z + a1.w*r1.w;
    uint4 p;
    p.x = pack2(a0.x, a0.y); p.y = pack2(a0.z, a0.w);
    p.z = pack2(a1.x, a1.y); p.w = pack2(a1.z, a1.w);
    *reinterpret_cast<uint4*>(AhB + (sn & 1) * 8192 + aw_off) = p;
  };

  f32x4_t acc[4][8];
#pragma unroll
  for (int mi = 0; mi < 4; ++mi)
#pragma unroll
    for (int ni = 0; ni < 8; ++ni)
      acc[mi][ni] = f32x4_t{0.f, 0.f, 0.f, 0.f};

  // ---- prologue: A(0)->regs, B(0),B(1) DMA; lin(0); write A(0) bf16 ----
  {
    const float4 a0 = *reinterpret_cast<const float4*>(gA);
    const float4 a1 = *reinterpret_cast<const float4*>(gA + 16);
    const float4 r0 = *reinterpret_cast<const float4*>(gR);
    const float4 r1 = *reinterpret_cast<const float4*>(gR + 16);
    __builtin_amdgcn_sched_barrier(0);
    stageB(0);
    stageB(1);
    __builtin_amdgcn_sched_barrier(0);
    if (t < BM) mlp_acc[t] = 0.f;
    stageA_math(0, a0, a1, r0, r1);
    asm volatile("s_waitcnt vmcnt(4) lgkmcnt(0)" ::: "memory");
    __builtin_amdgcn_s_barrier();
  }

  // ---- steady-state steps 0..29 ----
  for (int s = 0; s < 30; ++s) {
    const int rb = (s % 3) * 32768;
    const int ab = (s & 1) * 8192;
    // issue next A/rep loads first (longest latency)
    const float4 a0 = *reinterpret_cast<const float4*>(gA + (s + 1) * 128);
    const float4 a1 = *reinterpret_cast<const float4*>(gA + (s + 1) * 128 + 16);
    const float4 r0 = *reinterpret_cast<const float4*>(gR + (s + 1) * 128);
    const float4 r1 = *reinterpret_cast<const float4*>(gR + (s + 1) * 128 + 16);
    // ds_reads of current tiles
    bf16x8_t bfr[8], afr[4];
#pragma unroll
    for (int ni = 0; ni < 8; ++ni)
      bfr[ni] = *reinterpret_cast<const bf16x8_t*>(BhB + rb + br_base + ni * 1024);
#pragma unroll
    for (int mi = 0; mi < 4; ++mi)
      afr[mi] = *reinterpret_cast<const bf16x8_t*>(AhB + ab + ar_base + mi * 1024);
    __builtin_amdgcn_sched_barrier(0);
    stageB(s + 2);                       // DMA issued AFTER ds_reads (m201 order)
    __builtin_amdgcn_sched_barrier(0);
    __builtin_amdgcn_s_setprio(1);
#pragma unroll
    for (int mi = 0; mi < 4; ++mi)
#pragma unroll
      for (int ni = 0; ni < 8; ++ni)
        acc[mi][ni] = __builtin_amdgcn_mfma_f32_16x16x32_bf16(afr[mi], bfr[ni], acc[mi][ni], 0, 0, 0);
    __builtin_amdgcn_s_setprio(0);
    stageA_math(s + 1, a0, a1, r0, r1);  // compiler waits vmcnt(4) here (leaves B DMAs)
    asm volatile("s_waitcnt vmcnt(4) lgkmcnt(0)" ::: "memory");
    __builtin_amdgcn_s_barrier();
  }

  // ---- step 30 (stage A(31), no more B) ----
  {
    const int s = 30;
    const float4 a0 = *reinterpret_cast<const float4*>(gA + 31 * 128);
    const float4 a1 = *reinterpret_cast<const float4*>(gA + 31 * 128 + 16);
    const float4 r0 = *reinterpret_cast<const float4*>(gR + 31 * 128);
    const float4 r1 = *reinterpret_cast<const float4*>(gR + 31 * 128 + 16);
    bf16x8_t bfr[8], afr[4];
#pragma unroll
    for (int ni = 0; ni < 8; ++ni)
      bfr[ni] = *reinterpret_cast<const bf16x8_t*>(BhB + (s % 3) * 32768 + br_base + ni * 1024);
#pragma unroll
    for (int mi = 0; mi < 4; ++mi)
      afr[mi] = *reinterpret_cast<const bf16x8_t*>(AhB + (s & 1) * 8192 + ar_base + mi * 1024);
#pragma unroll
    for (int mi = 0; mi < 4; ++mi)
#pragma unroll
      for (int ni = 0; ni < 8; ++ni)
        acc[mi][ni] = __builtin_amdgcn_mfma_f32_16x16x32_bf16(afr[mi], bfr[ni], acc[mi][ni], 0, 0, 0);
    stageA_math(31, a0, a1, r0, r1);
    asm volatile("s_waitcnt vmcnt(0) lgkmcnt(0)" ::: "memory");
    __builtin_amdgcn_s_barrier();
  }
  // ---- step 31 ----
  {
    bf16x8_t bfr[8], afr[4];
#pragma unroll
    for (int ni = 0; ni < 8; ++ni)
      bfr[ni] = *reinterpret_cast<const bf16x8_t*>(BhB + (31 % 3) * 32768 + br_base + ni * 1024);
#pragma unroll
    for (int mi = 0; mi < 4; ++mi)
      afr[mi] = *reinterpret_cast<const bf16x8_t*>(AhB + 8192 + ar_base + mi * 1024);
#pragma unroll
    for (int mi = 0; mi < 4; ++mi)
#pragma unroll
      for (int ni = 0; ni < 8; ++ni)
        acc[mi][ni] = __builtin_amdgcn_mfma_f32_16x16x32_bf16(afr[mi], bfr[ni], acc[mi][ni], 0, 0, 0);
  }

  // ---- epilogue ----
  linreg += __shfl_xor(linreg, 1);
  linreg += __shfl_xor(linreg, 2);
  if (cq == 0) lin_acc[R] = linreg;

  float b1r[8], ar[8];
#pragma unroll
  for (int ni = 0; ni < 8; ++ni) {
    const int c = wn * 128 + ni * 16 + fr;
    b1r[ni] = b1[c];
    ar[ni]  = aw[c];
  }
#pragma unroll
  for (int mi = 0; mi < 4; ++mi) {
#pragma unroll
    for (int r = 0; r < 4; ++r) {
      float sum = 0.f;
#pragma unroll
      for (int ni = 0; ni < 8; ++ni) {
        const float h = acc[mi][ni][r] + b1r[ni];
        sum += fmaxf(h, 0.f) * ar[ni];
      }
      sum += __shfl_xor(sum, 1);
      sum += __shfl_xor(sum, 2);
      sum += __shfl_xor(sum, 4);
      sum += __shfl_xor(sum, 8);
      if (fr == 0) {
        const int row = wm * 64 + mi * 16 + kg * 4 + r;
        atomicAdd(&mlp_acc[row], sum);
      }
    }
  }
  __syncthreads();
  if (t < BM)
    out[blockRow + t] = lin_acc[t] + mlp_acc[t] + b2p[0];
}

extern "C" void kernel_launch(void* const* d_in, const int* in_sizes, int n_in,
                              void* d_out, int out_size, void* d_ws, size_t ws_size,
                              hipStream_t stream) {
  const float* X     = (const float*)d_in[0];
  const float* y     = (const float*)d_in[1];
  const float* Xs    = (const float*)d_in[2];
  const float* gamma = (const float*)d_in[3];
  const float* W     = (const float*)d_in[4];
  const float* a     = (const float*)d_in[5];
  const float* b1    = (const float*)d_in[6];
  const float* b2    = (const float*)d_in[7];
  float* out = (float*)d_out;

  char* ws = (char*)d_ws;
  float*  v       = (float*)(ws + 0);
  float*  u1      = (float*)(ws + 4096);
  float*  u2      = (float*)(ws + 8192);
  float*  rep_lin = (float*)(ws + 12288);
  float*  repn    = (float*)(ws + 16384);
  ushort* WnF     = (ushort*)(ws + 20480);

  hipMemsetAsync(ws, 0, 3 * 4096, stream);
  hipLaunchKernelGGL(xty_kernel,     dim3(256), dim3(256), 0, stream, X, y, v);
  hipLaunchKernelGGL(xtxw_kernel,    dim3(256), dim3(256), 0, stream, X, v, u1);
  hipLaunchKernelGGL(xtxw_kernel,    dim3(256), dim3(256), 0, stream, X, u1, u2);
  hipLaunchKernelGGL(combine_kernel, dim3(1),   dim3(256), 0, stream, v, u1, u2, gamma, rep_lin, repn);
  hipLaunchKernelGGL(wn_frag_kernel, dim3(256), dim3(256), 0, stream, W, repn, WnF);
  hipLaunchKernelGGL(fused_kernel,   dim3(K_ROWS / BM), dim3(512), 0, stream,
                     Xs, WnF, rep_lin, b1, a, b2, out);
}